// Round 2
// 166.499 us; speedup vs baseline: 1.0317x; 1.0317x over previous
//
#include <hip/hip_runtime.h>

#define NN 32
#define DD 128
#define SS 128
#define MM 64
#define PP 4096              // MM*MM
#define DSZ (DD * SS)

typedef short bf16x8 __attribute__((ext_vector_type(8)));
typedef float f32x4  __attribute__((ext_vector_type(4)));
typedef unsigned int u32x2 __attribute__((ext_vector_type(2)));

// Workspace layout (float offsets)
#define OFF_CPK 0                          // fp32 planes [5][D][S] (plane 1 unused)
#define OFF_C1T (OFF_CPK + 5 * DSZ)        // c1 transposed bf16 [S][D]
#define OFF_MC  (OFF_C1T + DSZ / 2)        // column means [N][D][M]
#define OFF_DG  (OFF_MC + NN * DD * MM)    // diagonals    [N][D][M]
#define OFF_MD  (OFF_DG + NN * DD * MM)    // mean(diag)   [N][D]
#define OFF_MA  (OFF_MD + NN * DD)         // mean(all)    [N][D]
#define OFF_UP  (OFF_MA + NN * DD)         // u' [N][S][M]

__device__ __forceinline__ unsigned int fbits(float f) {
    union { float f; unsigned int u; } c; c.f = f; return c.u;
}

// ---------------------------------------------------------------------------
// Kernel 1: stats (blocks 0..1023) + coeff pack (blocks 1024..1087), fused by
// block range. Stats: 4 waves/block, one 64x64 matrix per wave, coalesced 1KB
// wave reads. Pack: coeffs [D,S,5] AoS -> fp32 planes + c1t bf16 [S][D] (RNE).
// ---------------------------------------------------------------------------
__global__ __launch_bounds__(256) void stats_pack_k(const float* __restrict__ x,
                                                    const float* __restrict__ coeffs,
                                                    float* __restrict__ cpk,
                                                    unsigned short* __restrict__ c1t,
                                                    float* __restrict__ mc,
                                                    float* __restrict__ dg,
                                                    float* __restrict__ md,
                                                    float* __restrict__ ma) {
    if (blockIdx.x >= (NN * DD / 4)) {
        // ---- pack path ----
        int g = (blockIdx.x - NN * DD / 4) * 256 + threadIdx.x;   // g = d*S + s
        int d = g >> 7, s = g & 127;
        float v0 = coeffs[g * 5 + 0];
        float v1 = coeffs[g * 5 + 1];
        float v2 = coeffs[g * 5 + 2];
        float v3 = coeffs[g * 5 + 3];
        float v4 = coeffs[g * 5 + 4];
        cpk[0 * DSZ + g] = v0;
        cpk[2 * DSZ + g] = v2;
        cpk[3 * DSZ + g] = v3;
        cpk[4 * DSZ + g] = v4;
        unsigned int u = fbits(v1);
        u += 0x7fffu + ((u >> 16) & 1);           // round to nearest even
        c1t[s * DD + d] = (unsigned short)(u >> 16);
        return;
    }
    // ---- stats path ----
    int nd = blockIdx.x * 4 + (threadIdx.x >> 6);
    int l  = threadIdx.x & 63;
    const float* base = x + (size_t)nd * PP;
    int iq = l >> 4, jq = l & 15;

    float4 cs = make_float4(0.f, 0.f, 0.f, 0.f);
    float dv = 0.f;
#pragma unroll
    for (int r = 0; r < 16; ++r) {
        float4 v = *(const float4*)(base + (r * 4 + iq) * MM + jq * 4);
        cs.x += v.x; cs.y += v.y; cs.z += v.z; cs.w += v.w;
        if (r == jq)   // this lane's tile contains diag element i = 4*jq + iq
            dv = (iq == 0) ? v.x : (iq == 1) ? v.y : (iq == 2) ? v.z : v.w;
    }
#pragma unroll
    for (int m = 16; m <= 32; m <<= 1) {
        cs.x += __shfl_xor(cs.x, m);
        cs.y += __shfl_xor(cs.y, m);
        cs.z += __shfl_xor(cs.z, m);
        cs.w += __shfl_xor(cs.w, m);
    }
    if (iq == 0) {
        float4 o = make_float4(cs.x * (1.f / 64.f), cs.y * (1.f / 64.f),
                               cs.z * (1.f / 64.f), cs.w * (1.f / 64.f));
        *(float4*)(mc + nd * MM + jq * 4) = o;
    }
    dg[nd * MM + 4 * jq + iq] = dv;
    float dsum = dv;
#pragma unroll
    for (int m = 1; m <= 32; m <<= 1) dsum += __shfl_xor(dsum, m);
    float tot = cs.x + cs.y + cs.z + cs.w;
#pragma unroll
    for (int m = 1; m <= 8; m <<= 1) tot += __shfl_xor(tot, m);
    if (l == 0) {
        md[nd] = dsum * (1.f / 64.f);
        ma[nd] = tot * (1.f / 4096.f);
    }
}

// ---------------------------------------------------------------------------
// Kernel 2: u'[n][s][i] = 0.5*( sum_d c0*mc + c2*dg  +  sum_d c3*md + c4*ma + bias[s] )
// (unchanged — measured-fine control variable)
// ---------------------------------------------------------------------------
__global__ __launch_bounds__(256) void combine_k(const float* __restrict__ cpk,
                                                 const float* __restrict__ mc,
                                                 const float* __restrict__ dg,
                                                 const float* __restrict__ md,
                                                 const float* __restrict__ ma,
                                                 const float* __restrict__ bias,
                                                 float* __restrict__ up) {
    int sg = blockIdx.x, n = blockIdx.y;
    int t  = threadIdx.x;
    int i  = t & 63;
    int sq = t >> 6;                 // 0..3 (wave-uniform)
    int s0 = sg * 16 + sq * 4;

    const float* c0p = cpk + 0 * DSZ;
    const float* c2p = cpk + 2 * DSZ;
    const float* c3p = cpk + 3 * DSZ;
    const float* c4p = cpk + 4 * DSZ;

    float wacc[4] = {0.f, 0.f, 0.f, 0.f};
    float vacc[4] = {0.f, 0.f, 0.f, 0.f};
#pragma unroll 2
    for (int d = 0; d < DD; ++d) {
        int bidx = (n * DD + d) * MM + i;
        float m  = mc[bidx];
        float g  = dg[bidx];
        float mdv = md[n * DD + d];
        float mav = ma[n * DD + d];
#pragma unroll
        for (int r = 0; r < 4; ++r) {
            int cs = d * SS + s0 + r;
            wacc[r] += c0p[cs] * m + c2p[cs] * g;
            vacc[r] += c3p[cs] * mdv + c4p[cs] * mav;
        }
    }
#pragma unroll
    for (int r = 0; r < 4; ++r) {
        int s = s0 + r;
        up[((size_t)n * SS + s) * MM + i] = 0.5f * (wacc[r] + vacc[r] + bias[s]);
    }
}

// ---------------------------------------------------------------------------
// Kernel 3: MFMA GEMM, LDS-staged B path (NO inline asm, NO tr-read).
// out[n,s,p] = sum_d c1[d,s]*x[n,d,p] + u'[s,i] + u'[s,j]
// Block (p-tile 128, n), 4 waves (2s x 2p of 64x64). Whole K=128 staged ONCE.
// Staging: each thread loads a 4k x 4p fp32 block (float4, coalesced 512B wave
// rows), v_perm-packs to bf16, in-register transpose, writes k-contiguous 8B
// chunks to a [p][k] bf16 tile with T2 XOR swizzle:
//     byte' = (p*256 + 2k) ^ (((p ^ (p>>3)) & 7) << 4)
// Reads: B-frag = ONE ds_read_b128 (8 contiguous k's) at the same swizzled
// address -> elements in exactly the order written (k ascending). Reads 2-way
// bank-aliased (free), writes 4-way (short phase). A-frags from global c1t
// (L2-hot). Epilogue reads u' straight from global (L2-resident).
// ---------------------------------------------------------------------------
__global__ __launch_bounds__(256, 3) void gemm_k(const float* __restrict__ x,
                                                 const unsigned short* __restrict__ c1t,
                                                 const float* __restrict__ up,
                                                 float* __restrict__ out) {
    __shared__ unsigned short xs[128 * 128];   // 32 KiB bf16 [p][k], XOR-swizzled

    int n  = blockIdx.y;
    int p0 = blockIdx.x * 128;
    int t  = threadIdx.x;

    // ---- stage x[n, k=0..128, p0..p0+128) -> bf16 LDS, k-major per p ----
    {
        int u  = t & 31;               // 32 lanes cover a 512B row (128 p)
        int kq = t >> 5;               // 8 k-groups
        int pl = u * 4;
        const float* xb = x + (size_t)n * DD * PP + p0 + pl;
#pragma unroll
        for (int pp = 0; pp < 4; ++pp) {
            int k4 = pp * 32 + kq * 4;
            float4 v0 = *(const float4*)(xb + (size_t)(k4 + 0) * PP);
            float4 v1 = *(const float4*)(xb + (size_t)(k4 + 1) * PP);
            float4 v2 = *(const float4*)(xb + (size_t)(k4 + 2) * PP);
            float4 v3 = *(const float4*)(xb + (size_t)(k4 + 3) * PP);
#pragma unroll
            for (int i = 0; i < 4; ++i) {   // fully unrolled: static indexing
                float a0 = (i == 0) ? v0.x : (i == 1) ? v0.y : (i == 2) ? v0.z : v0.w;
                float a1 = (i == 0) ? v1.x : (i == 1) ? v1.y : (i == 2) ? v1.z : v1.w;
                float a2 = (i == 0) ? v2.x : (i == 1) ? v2.y : (i == 2) ? v2.z : v2.w;
                float a3 = (i == 0) ? v3.x : (i == 1) ? v3.y : (i == 2) ? v3.z : v3.w;
                int p = pl + i;
                u32x2 wv;
                wv.x = __builtin_amdgcn_perm(fbits(a1), fbits(a0), 0x07060302u);
                wv.y = __builtin_amdgcn_perm(fbits(a3), fbits(a2), 0x07060302u);
                int boff = (p * 256 + 2 * k4) ^ (((p ^ (p >> 3)) & 7) << 4);
                *(u32x2*)((char*)xs + boff) = wv;
            }
        }
    }
    __syncthreads();

    int w = t >> 6, l = t & 63;
    int wp = w & 1, wsn = w >> 1;
    int q = l >> 4, c = l & 15;
    int s0w = wsn * 64;
    int p0w = p0 + wp * 64;            // global p base of this wave
    int plw = wp * 64;                 // local  p base of this wave

    f32x4 acc[4][4];
#pragma unroll
    for (int a = 0; a < 4; ++a)
#pragma unroll
        for (int b = 0; b < 4; ++b) acc[a][b] = (f32x4)0.f;

#pragma unroll
    for (int kt = 0; kt < 4; ++kt) {
        int k0 = kt * 32 + q * 8;
        bf16x8 af[4];
#pragma unroll
        for (int st = 0; st < 4; ++st)
            af[st] = *(const bf16x8*)(c1t + (size_t)(s0w + st * 16 + c) * DD + k0);

        bf16x8 bfr[4];
#pragma unroll
        for (int pt = 0; pt < 4; ++pt) {
            int p = plw + pt * 16 + c;
            int boff = (p * 256 + 2 * k0) ^ (((p ^ (p >> 3)) & 7) << 4);
            bfr[pt] = *(const bf16x8*)((const char*)xs + boff);
        }

#pragma unroll
        for (int pt = 0; pt < 4; ++pt)
#pragma unroll
            for (int st = 0; st < 4; ++st)
                acc[st][pt] = __builtin_amdgcn_mfma_f32_16x16x32_bf16(af[st], bfr[pt],
                                                                     acc[st][pt], 0, 0, 0);
    }

    // ---- epilogue: out = acc + u'[s,i] + u'[s,j], u' straight from global ----
    int iw = p0w >> 6;                          // wave-uniform i index
    const float* upn = up + (size_t)n * SS * MM;
#pragma unroll
    for (int st = 0; st < 4; ++st) {
#pragma unroll
        for (int r = 0; r < 4; ++r) {
            int s = s0w + st * 16 + q * 4 + r;
            const float* urow = upn + (size_t)s * MM;
            float uiv = urow[iw];
            float* orow = out + ((size_t)(n * SS + s)) * PP + p0w;
#pragma unroll
            for (int pt = 0; pt < 4; ++pt) {
                int j = pt * 16 + c;            // p0w is 64-aligned -> j = p & 63
                orow[j] = acc[st][pt][r] + uiv + urow[j];
            }
        }
    }
}

// ---------------------------------------------------------------------------
extern "C" void kernel_launch(void* const* d_in, const int* in_sizes, int n_in,
                              void* d_out, int out_size, void* d_ws, size_t ws_size,
                              hipStream_t stream) {
    const float* x      = (const float*)d_in[0];   // [N,D,M,M]
    const float* coeffs = (const float*)d_in[1];   // [D,S,5]
    const float* bias   = (const float*)d_in[2];   // [S]
    float* out = (float*)d_out;
    float* ws  = (float*)d_ws;

    float*          cpk = ws + OFF_CPK;
    unsigned short* c1t = (unsigned short*)(ws + OFF_C1T);
    float*          mc  = ws + OFF_MC;
    float*          dg  = ws + OFF_DG;
    float*          md  = ws + OFF_MD;
    float*          ma  = ws + OFF_MA;
    float*          up  = ws + OFF_UP;

    stats_pack_k<<<NN * DD / 4 + DSZ / 256, 256, 0, stream>>>(x, coeffs, cpk, c1t,
                                                              mc, dg, md, ma);
    combine_k<<<dim3(8, NN), 256, 0, stream>>>(cpk, mc, dg, md, ma, bias, up);
    gemm_k<<<dim3(PP / 128, NN), 256, 0, stream>>>(x, c1t, up, out);
}

// Round 3
// 157.771 us; speedup vs baseline: 1.0887x; 1.0553x over previous
//
#include <hip/hip_runtime.h>

#define NN 32
#define DD 128
#define SS 128
#define MM 64
#define PP 4096              // MM*MM
#define DSZ (DD * SS)

typedef short bf16x8 __attribute__((ext_vector_type(8)));
typedef float f32x4  __attribute__((ext_vector_type(4)));
typedef unsigned int u32x2 __attribute__((ext_vector_type(2)));

// Workspace layout (float offsets)
#define OFF_CPK 0                          // fp32 planes [5][D][S] (plane 1 unused)
#define OFF_C1T (OFF_CPK + 5 * DSZ)        // c1 transposed bf16 [S][D]
#define OFF_MC  (OFF_C1T + DSZ / 2)        // column means [N][D][M]
#define OFF_DG  (OFF_MC + NN * DD * MM)    // diagonals    [N][D][M]
#define OFF_MD  (OFF_DG + NN * DD * MM)    // mean(diag)   [N][D]
#define OFF_MA  (OFF_MD + NN * DD)         // mean(all)    [N][D]
#define OFF_UP  (OFF_MA + NN * DD)         // u' [N][S][M]

__device__ __forceinline__ unsigned int fbits(float f) {
    union { float f; unsigned int u; } c; c.f = f; return c.u;
}

// ---------------------------------------------------------------------------
// Kernel 1: stats (blocks 0..1023) + coeff pack (blocks 1024..1087), fused by
// block range. Stats: 4 waves/block, one 64x64 matrix per wave, coalesced 1KB
// wave reads. Pack: coeffs [D,S,5] AoS -> fp32 planes + c1t bf16 [S][D] (RNE).
// ---------------------------------------------------------------------------
__global__ __launch_bounds__(256) void stats_pack_k(const float* __restrict__ x,
                                                    const float* __restrict__ coeffs,
                                                    float* __restrict__ cpk,
                                                    unsigned short* __restrict__ c1t,
                                                    float* __restrict__ mc,
                                                    float* __restrict__ dg,
                                                    float* __restrict__ md,
                                                    float* __restrict__ ma) {
    if (blockIdx.x >= (NN * DD / 4)) {
        // ---- pack path ----
        int g = (blockIdx.x - NN * DD / 4) * 256 + threadIdx.x;   // g = d*S + s
        int d = g >> 7, s = g & 127;
        float v0 = coeffs[g * 5 + 0];
        float v1 = coeffs[g * 5 + 1];
        float v2 = coeffs[g * 5 + 2];
        float v3 = coeffs[g * 5 + 3];
        float v4 = coeffs[g * 5 + 4];
        cpk[0 * DSZ + g] = v0;
        cpk[2 * DSZ + g] = v2;
        cpk[3 * DSZ + g] = v3;
        cpk[4 * DSZ + g] = v4;
        unsigned int u = fbits(v1);
        u += 0x7fffu + ((u >> 16) & 1);           // round to nearest even
        c1t[s * DD + d] = (unsigned short)(u >> 16);
        return;
    }
    // ---- stats path ----
    int nd = blockIdx.x * 4 + (threadIdx.x >> 6);
    int l  = threadIdx.x & 63;
    const float* base = x + (size_t)nd * PP;
    int iq = l >> 4, jq = l & 15;

    float4 cs = make_float4(0.f, 0.f, 0.f, 0.f);
    float dv = 0.f;
#pragma unroll
    for (int r = 0; r < 16; ++r) {
        float4 v = *(const float4*)(base + (r * 4 + iq) * MM + jq * 4);
        cs.x += v.x; cs.y += v.y; cs.z += v.z; cs.w += v.w;
        if (r == jq)   // this lane's tile contains diag element i = 4*jq + iq
            dv = (iq == 0) ? v.x : (iq == 1) ? v.y : (iq == 2) ? v.z : v.w;
    }
#pragma unroll
    for (int m = 16; m <= 32; m <<= 1) {
        cs.x += __shfl_xor(cs.x, m);
        cs.y += __shfl_xor(cs.y, m);
        cs.z += __shfl_xor(cs.z, m);
        cs.w += __shfl_xor(cs.w, m);
    }
    if (iq == 0) {
        float4 o = make_float4(cs.x * (1.f / 64.f), cs.y * (1.f / 64.f),
                               cs.z * (1.f / 64.f), cs.w * (1.f / 64.f));
        *(float4*)(mc + nd * MM + jq * 4) = o;
    }
    dg[nd * MM + 4 * jq + iq] = dv;
    float dsum = dv;
#pragma unroll
    for (int m = 1; m <= 32; m <<= 1) dsum += __shfl_xor(dsum, m);
    float tot = cs.x + cs.y + cs.z + cs.w;
#pragma unroll
    for (int m = 1; m <= 8; m <<= 1) tot += __shfl_xor(tot, m);
    if (l == 0) {
        md[nd] = dsum * (1.f / 64.f);
        ma[nd] = tot * (1.f / 4096.f);
    }
}

// ---------------------------------------------------------------------------
// Kernel 2: u'[n][s][i] = 0.5*( sum_d c0*mc + c2*dg + c3*md + c4*ma + bias[s] )
// Widened: grid (32 sg, N), 1 s per thread -> 1024 blocks (4/CU, 16 waves/CU)
// instead of 256 (1/CU). Same d-order accumulation (numerics identical).
// ---------------------------------------------------------------------------
__global__ __launch_bounds__(256) void combine_k(const float* __restrict__ cpk,
                                                 const float* __restrict__ mc,
                                                 const float* __restrict__ dg,
                                                 const float* __restrict__ md,
                                                 const float* __restrict__ ma,
                                                 const float* __restrict__ bias,
                                                 float* __restrict__ up) {
    int sg = blockIdx.x, n = blockIdx.y;
    int t  = threadIdx.x;
    int i  = t & 63;
    int sq = t >> 6;                 // 0..3 (wave-uniform)
    int s  = sg * 4 + sq;

    const float* c0p = cpk + 0 * DSZ;
    const float* c2p = cpk + 2 * DSZ;
    const float* c3p = cpk + 3 * DSZ;
    const float* c4p = cpk + 4 * DSZ;

    float wacc = 0.f;
    float vacc = 0.f;
#pragma unroll 4
    for (int d = 0; d < DD; ++d) {
        int bidx = (n * DD + d) * MM + i;
        float m   = mc[bidx];
        float g   = dg[bidx];
        float mdv = md[n * DD + d];
        float mav = ma[n * DD + d];
        int cs = d * SS + s;
        wacc += c0p[cs] * m + c2p[cs] * g;
        vacc += c3p[cs] * mdv + c4p[cs] * mav;
    }
    up[((size_t)n * SS + s) * MM + i] = 0.5f * (wacc + vacc + bias[s]);
}

// ---------------------------------------------------------------------------
// Kernel 3: MFMA GEMM, LDS-staged B path (verified round-2 structure).
// out[n,s,p] = sum_d c1[d,s]*x[n,d,p] + u'[s,i] + u'[s,j]
// Changes this round: __launch_bounds__(256,4) (16 waves/CU, LDS 4x32=128KiB)
// and staging restructured to keep 8 float4 loads in flight (same pack order,
// same XOR swizzle -> numerics identical to the passing round-2 kernel).
//   LDS layout: byte' = (p*256 + 2k) ^ (((p ^ (p>>3)) & 7) << 4)
// ---------------------------------------------------------------------------
__global__ __launch_bounds__(256, 4) void gemm_k(const float* __restrict__ x,
                                                 const unsigned short* __restrict__ c1t,
                                                 const float* __restrict__ up,
                                                 float* __restrict__ out) {
    __shared__ unsigned short xs[128 * 128];   // 32 KiB bf16 [p][k], XOR-swizzled

    int n  = blockIdx.y;
    int p0 = blockIdx.x * 128;
    int t  = threadIdx.x;

    // ---- stage x[n, k=0..128, p0..p0+128) -> bf16 LDS, k-major per p ----
    {
        int u  = t & 31;               // 32 lanes cover a 512B row (128 p)
        int kq = t >> 5;               // 8 k-groups
        int pl = u * 4;
        const float* xb = x + (size_t)n * DD * PP + p0 + pl;
#pragma unroll
        for (int ph = 0; ph < 2; ++ph) {            // two halves of K
            int k4a = (2 * ph + 0) * 32 + kq * 4;
            int k4b = (2 * ph + 1) * 32 + kq * 4;
            float4 va0 = *(const float4*)(xb + (size_t)(k4a + 0) * PP);
            float4 va1 = *(const float4*)(xb + (size_t)(k4a + 1) * PP);
            float4 va2 = *(const float4*)(xb + (size_t)(k4a + 2) * PP);
            float4 va3 = *(const float4*)(xb + (size_t)(k4a + 3) * PP);
            float4 vb0 = *(const float4*)(xb + (size_t)(k4b + 0) * PP);
            float4 vb1 = *(const float4*)(xb + (size_t)(k4b + 1) * PP);
            float4 vb2 = *(const float4*)(xb + (size_t)(k4b + 2) * PP);
            float4 vb3 = *(const float4*)(xb + (size_t)(k4b + 3) * PP);
#pragma unroll
            for (int i = 0; i < 4; ++i) {   // fully unrolled: static indexing
                float a0 = (i == 0) ? va0.x : (i == 1) ? va0.y : (i == 2) ? va0.z : va0.w;
                float a1 = (i == 0) ? va1.x : (i == 1) ? va1.y : (i == 2) ? va1.z : va1.w;
                float a2 = (i == 0) ? va2.x : (i == 1) ? va2.y : (i == 2) ? va2.z : va2.w;
                float a3 = (i == 0) ? va3.x : (i == 1) ? va3.y : (i == 2) ? va3.z : va3.w;
                int p = pl + i;
                u32x2 wv;
                wv.x = __builtin_amdgcn_perm(fbits(a1), fbits(a0), 0x07060302u);
                wv.y = __builtin_amdgcn_perm(fbits(a3), fbits(a2), 0x07060302u);
                int boff = (p * 256 + 2 * k4a) ^ (((p ^ (p >> 3)) & 7) << 4);
                *(u32x2*)((char*)xs + boff) = wv;
            }
#pragma unroll
            for (int i = 0; i < 4; ++i) {
                float a0 = (i == 0) ? vb0.x : (i == 1) ? vb0.y : (i == 2) ? vb0.z : vb0.w;
                float a1 = (i == 0) ? vb1.x : (i == 1) ? vb1.y : (i == 2) ? vb1.z : vb1.w;
                float a2 = (i == 0) ? vb2.x : (i == 1) ? vb2.y : (i == 2) ? vb2.z : vb2.w;
                float a3 = (i == 0) ? vb3.x : (i == 1) ? vb3.y : (i == 2) ? vb3.z : vb3.w;
                int p = pl + i;
                u32x2 wv;
                wv.x = __builtin_amdgcn_perm(fbits(a1), fbits(a0), 0x07060302u);
                wv.y = __builtin_amdgcn_perm(fbits(a3), fbits(a2), 0x07060302u);
                int boff = (p * 256 + 2 * k4b) ^ (((p ^ (p >> 3)) & 7) << 4);
                *(u32x2*)((char*)xs + boff) = wv;
            }
        }
    }
    __syncthreads();

    int w = t >> 6, l = t & 63;
    int wp = w & 1, wsn = w >> 1;
    int q = l >> 4, c = l & 15;
    int s0w = wsn * 64;
    int p0w = p0 + wp * 64;            // global p base of this wave
    int plw = wp * 64;                 // local  p base of this wave

    f32x4 acc[4][4];
#pragma unroll
    for (int a = 0; a < 4; ++a)
#pragma unroll
        for (int b = 0; b < 4; ++b) acc[a][b] = (f32x4)0.f;

#pragma unroll
    for (int kt = 0; kt < 4; ++kt) {
        int k0 = kt * 32 + q * 8;
        bf16x8 af[4];
#pragma unroll
        for (int st = 0; st < 4; ++st)
            af[st] = *(const bf16x8*)(c1t + (size_t)(s0w + st * 16 + c) * DD + k0);

        bf16x8 bfr[4];
#pragma unroll
        for (int pt = 0; pt < 4; ++pt) {
            int p = plw + pt * 16 + c;
            int boff = (p * 256 + 2 * k0) ^ (((p ^ (p >> 3)) & 7) << 4);
            bfr[pt] = *(const bf16x8*)((const char*)xs + boff);
        }

#pragma unroll
        for (int pt = 0; pt < 4; ++pt)
#pragma unroll
            for (int st = 0; st < 4; ++st)
                acc[st][pt] = __builtin_amdgcn_mfma_f32_16x16x32_bf16(af[st], bfr[pt],
                                                                     acc[st][pt], 0, 0, 0);
    }

    // ---- epilogue: out = acc + u'[s,i] + u'[s,j], u' straight from global ----
    int iw = p0w >> 6;                          // wave-uniform i index
    const float* upn = up + (size_t)n * SS * MM;
#pragma unroll
    for (int st = 0; st < 4; ++st) {
#pragma unroll
        for (int r = 0; r < 4; ++r) {
            int s = s0w + st * 16 + q * 4 + r;
            const float* urow = upn + (size_t)s * MM;
            float uiv = urow[iw];
            float* orow = out + ((size_t)(n * SS + s)) * PP + p0w;
#pragma unroll
            for (int pt = 0; pt < 4; ++pt) {
                int j = pt * 16 + c;            // p0w is 64-aligned -> j = p & 63
                orow[j] = acc[st][pt][r] + uiv + urow[j];
            }
        }
    }
}

// ---------------------------------------------------------------------------
extern "C" void kernel_launch(void* const* d_in, const int* in_sizes, int n_in,
                              void* d_out, int out_size, void* d_ws, size_t ws_size,
                              hipStream_t stream) {
    const float* x      = (const float*)d_in[0];   // [N,D,M,M]
    const float* coeffs = (const float*)d_in[1];   // [D,S,5]
    const float* bias   = (const float*)d_in[2];   // [S]
    float* out = (float*)d_out;
    float* ws  = (float*)d_ws;

    float*          cpk = ws + OFF_CPK;
    unsigned short* c1t = (unsigned short*)(ws + OFF_C1T);
    float*          mc  = ws + OFF_MC;
    float*          dg  = ws + OFF_DG;
    float*          md  = ws + OFF_MD;
    float*          ma  = ws + OFF_MA;
    float*          up  = ws + OFF_UP;

    stats_pack_k<<<NN * DD / 4 + DSZ / 256, 256, 0, stream>>>(x, coeffs, cpk, c1t,
                                                              mc, dg, md, ma);
    combine_k<<<dim3(32, NN), 256, 0, stream>>>(cpk, mc, dg, md, ma, bias, up);
    gemm_k<<<dim3(PP / 128, NN), 256, 0, stream>>>(x, c1t, up, out);
}